// Round 8
// baseline (203.475 us; speedup 1.0000x reference)
//
#include <hip/hip_runtime.h>
#include <math.h>

// GCN 2-layer, N=100000, E=3200000, feats 2->16->2.
// R8:
//  - k_degree deleted: k_pass2 fuses a 2048-bin LDS node histogram (it holds
//    all edges in registers anyway) and writes per-chunk partial counts;
//    k_node1 reduces 9 partials/node -> dinv, sx.
//  - agg kernels restructured for ILP: 256 thr/block, 3 guarded int4 slot
//    loads + 12 gathers issued up front, then 24 LDS atomics. R7's agg1 was
//    latency-bound (4 edges/thread, fully serialized chain, 44us @ 2% VALU).
// Partition: pass1 -> 49 coarse buckets (2048 nodes), pass2 -> 32 fine (64).

constexpr int N = 100000;
constexpr int LOGB = 6;
constexpr int BNODES = 1 << LOGB;             // 64 nodes / fine bucket
constexpr int K = (N + BNODES - 1) / BNODES;  // 1563 fine buckets with nodes
constexpr int KF = 49 * 32;                   // fine buckets allocated
constexpr int CAPF = 2560;                    // fine cap: mean 2048 + ~11 sigma
constexpr int NC = 49;                        // coarse buckets (dst>>11)
constexpr int CAP1 = 68608;                   // coarse cap: mean 65306 + ~13 sigma
constexpr int BSP = 512;
constexpr int ECHUNK = 8192;
constexpr int EPT = ECHUNK / BSP;             // 16 edges/thread in registers
constexpr int MAXCH = 9;                      // chunks per coarse region

__global__ __launch_bounds__(BSP) void k_pass1(const int* __restrict__ src,
                                               const int* __restrict__ dst, int E,
                                               int* __restrict__ gfill1,
                                               int* __restrict__ slotsC) {
    __shared__ int hist[NC];
    __shared__ int base[NC];
    int t = threadIdx.x;
    if (t < NC) hist[t] = 0;
    __syncthreads();
    int s[EPT], d[EPT];
    int ebase = blockIdx.x * ECHUNK + t * EPT;
#pragma unroll
    for (int k = 0; k < EPT / 4; k++) {
        int idx = ebase + 4 * k;
        if (idx + 3 < E) {
            *(int4*)(s + 4 * k) = *(const int4*)(src + idx);
            *(int4*)(d + 4 * k) = *(const int4*)(dst + idx);
        } else {
            for (int j = 0; j < 4; j++) {
                s[4 * k + j] = (idx + j < E) ? src[idx + j] : -1;
                d[4 * k + j] = (idx + j < E) ? dst[idx + j] : -1;
            }
        }
    }
#pragma unroll
    for (int k = 0; k < EPT; k++)
        if (d[k] >= 0) atomicAdd(&hist[d[k] >> 11], 1);
    __syncthreads();
    if (t < NC) {
        int c = hist[t];
        base[t] = c ? atomicAdd(&gfill1[t], c) : 0;  // device reservation atomic
        hist[t] = 0;                                  // reuse as cursor
    }
    __syncthreads();
#pragma unroll
    for (int k = 0; k < EPT; k++) {
        if (d[k] >= 0) {
            int bin = d[k] >> 11;
            int r = atomicAdd(&hist[bin], 1);  // LDS
            int pos = base[bin] + r;
            if (pos < CAP1) slotsC[bin * CAP1 + pos] = (s[k] << 11) | (d[k] & 2047);
        }
    }
}

// pass2: coarse region chunk -> 32 fine buckets + 2048-bin node-degree
// partial histogram (cntp[(c*MAXCH+j)*2048 + local]). No early return: idle
// chunks still write zeroed partials (ws is poisoned, not zeroed).
__global__ __launch_bounds__(BSP) void k_pass2(const int* __restrict__ gfill1,
                                               const int* __restrict__ slotsC,
                                               int* __restrict__ gfillF,
                                               int* __restrict__ slotsF,
                                               int* __restrict__ cntp) {
    __shared__ int hist[32];
    __shared__ int base[32];
    __shared__ int cnt[2048];
    int c = blockIdx.x / MAXCH;
    int j = blockIdx.x % MAXCH;
    int t = threadIdx.x;
    if (t < 32) hist[t] = 0;
    for (int i = t; i < 2048; i += BSP) cnt[i] = 0;
    __syncthreads();
    int fill = min(gfill1[c], CAP1);
    int e0 = j * ECHUNK;
    int e1 = min(fill, e0 + ECHUNK);
    const int* row = slotsC + c * CAP1;
    int v[EPT];
    int ebase = e0 + t * EPT;
#pragma unroll
    for (int k = 0; k < EPT / 4; k++) {
        int idx = ebase + 4 * k;
        if (idx + 3 < e1) {
            *(int4*)(v + 4 * k) = *(const int4*)(row + idx);
        } else {
            for (int jj = 0; jj < 4; jj++) v[4 * k + jj] = (idx + jj < e1) ? row[idx + jj] : -1;
        }
    }
#pragma unroll
    for (int k = 0; k < EPT; k++) {
        if (v[k] >= 0) {
            atomicAdd(&hist[(v[k] >> 6) & 31], 1);
            atomicAdd(&cnt[v[k] & 2047], 1);  // node degree (counts ALL edges)
        }
    }
    __syncthreads();
    if (t < 32) {
        int cc = hist[t];
        base[t] = cc ? atomicAdd(&gfillF[c * 32 + t], cc) : 0;
        hist[t] = 0;
    }
    __syncthreads();
#pragma unroll
    for (int k = 0; k < EPT; k++) {
        if (v[k] >= 0) {
            int b = (v[k] >> 6) & 31;
            int r = atomicAdd(&hist[b], 1);  // LDS
            int pos = base[b] + r;
            if (pos < CAPF)
                slotsF[(c * 32 + b) * CAPF + pos] = ((v[k] >> 11) << 6) | (v[k] & 63);
        }
    }
    // cnt stable since first sync; dump partial counts (coalesced int4)
    int* out = cntp + (size_t)blockIdx.x * 2048;
    *(int4*)(out + 4 * t) = *(const int4*)(cnt + 4 * t);
}

// node i: deg = sum of 9 chunk partials; dinv = rsqrt(deg+1); sx = x*dinv
__global__ void k_node1(const int* __restrict__ cntp, const float* __restrict__ x,
                        float* __restrict__ dinv, float2* __restrict__ sx) {
    int i = blockIdx.x * blockDim.x + threadIdx.x;
    if (i >= N) return;
    int c = i >> 11, l = i & 2047;
    const int* p = cntp + (size_t)c * MAXCH * 2048 + l;
    int s = 0;
#pragma unroll
    for (int j = 0; j < MAXCH; j++) s += p[j * 2048];
    float di = rsqrtf((float)(s + 1));
    dinv[i] = di;
    float2 xv = ((const float2*)x)[i];
    sx[i] = make_float2(xv.x * di, xv.y * di);
}

__device__ __forceinline__ int4 gload(const int* __restrict__ row, int j, int cnt) {
    if (j + 3 < cnt) return *(const int4*)(row + j);
    int4 p = make_int4(-1, -1, -1, -1);
    if (j + 0 < cnt) p.x = row[j + 0];
    if (j + 1 < cnt) p.y = row[j + 1];
    if (j + 2 < cnt) p.z = row[j + 2];
    if (j + 3 < cnt) p.w = row[j + 3];
    return p;
}

// layer1 aggregate: 12 edges/thread, all gathers issued before atomics.
__global__ __launch_bounds__(256) void k_agg1(const int* __restrict__ gfillF,
                                              const int* __restrict__ slotsF,
                                              const float* __restrict__ dinv,
                                              const float2* __restrict__ sx,
                                              const float* __restrict__ W1,
                                              const float* __restrict__ b1,
                                              const float* __restrict__ W2,
                                              float2* __restrict__ sz) {
    __shared__ float accX[BNODES], accY[BNODES];
    __shared__ float sW1[32], sb1[16], sW2[32];
    int t = threadIdx.x;
    if (t < 32) sW1[t] = W1[t];
    if (t >= 32 && t < 48) sb1[t - 32] = b1[t - 32];
    if (t >= 48 && t < 80) sW2[t - 48] = W2[t - 48];
    if (t < BNODES) { accX[t] = 0.f; accY[t] = 0.f; }
    __syncthreads();
    int b = blockIdx.x;
    int count = min(gfillF[b], CAPF);
    const int* row = slotsF + (size_t)b * CAPF;
    int pk[12];
    {
        int4 p0 = gload(row, 4 * t, count);
        int4 p1 = gload(row, 4 * t + 1024, count);
        int4 p2 = gload(row, 4 * t + 2048, count);  // 3072 >= CAPF
        pk[0] = p0.x; pk[1] = p0.y; pk[2] = p0.z; pk[3] = p0.w;
        pk[4] = p1.x; pk[5] = p1.y; pk[6] = p1.z; pk[7] = p1.w;
        pk[8] = p2.x; pk[9] = p2.y; pk[10] = p2.z; pk[11] = p2.w;
    }
    float2 vv[12];
#pragma unroll
    for (int m = 0; m < 12; m++) {
        int idx = (pk[m] >= 0) ? (pk[m] >> LOGB) : 0;  // clamped: gather always safe
        vv[m] = sx[idx];
    }
#pragma unroll
    for (int m = 0; m < 12; m++) {
        if (pk[m] >= 0) {
            atomicAdd(&accX[pk[m] & (BNODES - 1)], vv[m].x);
            atomicAdd(&accY[pk[m] & (BNODES - 1)], vv[m].y);
        }
    }
    __syncthreads();
    if (t < BNODES) {
        int node = b * BNODES + t;
        if (node < N) {
            float di = dinv[node];
            float2 sv = sx[node];
            float a0 = (accX[t] + sv.x) * di;
            float a1 = (accY[t] + sv.y) * di;
            float z0 = 0.f, z1 = 0.f;
#pragma unroll
            for (int k = 0; k < 16; k++) {
                float h = fmaf(a0, sW1[k], fmaf(a1, sW1[16 + k], sb1[k]));
                h = fmaxf(h, 0.f);
                z0 = fmaf(h, sW2[2 * k + 0], z0);
                z1 = fmaf(h, sW2[2 * k + 1], z1);
            }
            sz[node] = make_float2(z0 * di, z1 * di);
        }
    }
}

// layer2 aggregate + bias + log_softmax
__global__ __launch_bounds__(256) void k_agg2(const int* __restrict__ gfillF,
                                              const int* __restrict__ slotsF,
                                              const float* __restrict__ dinv,
                                              const float2* __restrict__ sz,
                                              const float* __restrict__ b2,
                                              float2* __restrict__ out) {
    __shared__ float accX[BNODES], accY[BNODES];
    int b = blockIdx.x, t = threadIdx.x;
    if (t < BNODES) { accX[t] = 0.f; accY[t] = 0.f; }
    __syncthreads();
    int count = min(gfillF[b], CAPF);
    const int* row = slotsF + (size_t)b * CAPF;
    int pk[12];
    {
        int4 p0 = gload(row, 4 * t, count);
        int4 p1 = gload(row, 4 * t + 1024, count);
        int4 p2 = gload(row, 4 * t + 2048, count);
        pk[0] = p0.x; pk[1] = p0.y; pk[2] = p0.z; pk[3] = p0.w;
        pk[4] = p1.x; pk[5] = p1.y; pk[6] = p1.z; pk[7] = p1.w;
        pk[8] = p2.x; pk[9] = p2.y; pk[10] = p2.z; pk[11] = p2.w;
    }
    float2 vv[12];
#pragma unroll
    for (int m = 0; m < 12; m++) {
        int idx = (pk[m] >= 0) ? (pk[m] >> LOGB) : 0;
        vv[m] = sz[idx];
    }
#pragma unroll
    for (int m = 0; m < 12; m++) {
        if (pk[m] >= 0) {
            atomicAdd(&accX[pk[m] & (BNODES - 1)], vv[m].x);
            atomicAdd(&accY[pk[m] & (BNODES - 1)], vv[m].y);
        }
    }
    __syncthreads();
    if (t < BNODES) {
        int node = b * BNODES + t;
        if (node < N) {
            float di = dinv[node];
            float2 sv = sz[node];
            float v0 = fmaf(accX[t] + sv.x, di, b2[0]);
            float v1 = fmaf(accY[t] + sv.y, di, b2[1]);
            float m = fmaxf(v0, v1);
            float lse = m + logf(expf(v0 - m) + expf(v1 - m));
            out[node] = make_float2(v0 - lse, v1 - lse);
        }
    }
}

extern "C" void kernel_launch(void* const* d_in, const int* in_sizes, int n_in,
                              void* d_out, int out_size, void* d_ws, size_t ws_size,
                              hipStream_t stream) {
    const float* x  = (const float*)d_in[0];
    const int*   ei = (const int*)d_in[1];
    const float* W1 = (const float*)d_in[2];
    const float* b1 = (const float*)d_in[3];
    const float* W2 = (const float*)d_in[4];
    const float* b2 = (const float*)d_in[5];

    const int E = in_sizes[1] / 2;
    const int* src = ei;
    const int* dst = ei + E;
    const int GP = (E + ECHUNK - 1) / ECHUNK;  // 391

    char* ws = (char*)d_ws;
    size_t off = 0;
    auto alloc = [&](size_t bytes) {
        char* p = ws + off;
        off += (bytes + 511) & ~size_t(511);
        return p;
    };
    int*    fills  = (int*)alloc((NC + KF) * sizeof(int));  // gfill1 + gfillF
    float*  dinv   = (float*)alloc(N * sizeof(float));
    float2* sx     = (float2*)alloc(N * sizeof(float2));
    float2* sz     = (float2*)alloc(N * sizeof(float2));
    int*    slotsC = (int*)alloc((size_t)NC * CAP1 * sizeof(int));        // 13.4 MB
    int*    slotsF = (int*)alloc((size_t)KF * CAPF * sizeof(int));        // 16.1 MB
    int*    cntp   = (int*)alloc((size_t)NC * MAXCH * 2048 * sizeof(int));// 3.6 MB
    int* gfill1 = fills;
    int* gfillF = fills + NC;

    hipMemsetAsync(fills, 0, (NC + KF) * sizeof(int), stream);

    k_pass1<<<GP, BSP, 0, stream>>>(src, dst, E, gfill1, slotsC);
    k_pass2<<<NC * MAXCH, BSP, 0, stream>>>(gfill1, slotsC, gfillF, slotsF, cntp);
    k_node1<<<(N + 255) / 256, 256, 0, stream>>>(cntp, x, dinv, sx);
    k_agg1<<<K, 256, 0, stream>>>(gfillF, slotsF, dinv, sx, W1, b1, W2, sz);
    k_agg2<<<K, 256, 0, stream>>>(gfillF, slotsF, dinv, sz, b2, (float2*)d_out);
}